// Round 1
// baseline (384.604 us; speedup 1.0000x reference)
//
#include <hip/hip_runtime.h>

#define BATCH 128
#define NCELL 2048

constexpr float BETA = 0.1f;
// dt/dx computed in double then truncated to f32, matching jnp.float32(DT/DX)
constexpr double DT = 0.002;
constexpr double DX = 10.0 / 2048.0;

__device__ __forceinline__ float flux(float u) {
    float u2 = u * u;
    return 0.5f * u * (3.0f - u2) +
           (BETA / 12.0f) * u2 * (0.75f - 2.0f * u + 1.5f * u2 - 0.25f * u2 * u2);
}

__device__ __forceinline__ float flux_prime_abs(float u) {
    float u2 = u * u;
    float u3 = u2 * u;
    float fp = 1.5f * (1.0f - u2) +
               (BETA / 12.0f) * (1.5f * u - 6.0f * u2 + 6.0f * u3 - 1.5f * u2 * u3);
    return fabsf(fp);
}

// One block per batch row. 1024 threads; thread t owns cells t and t+1024.
// Whole row lives in LDS; 255 time steps in-kernel; each step streams u_new
// to the trajectory output (write-only, coalesced).
__global__ __launch_bounds__(1024)
void VariantCoeLinear1d_kernel(const float* __restrict__ init,
                               const int* __restrict__ stepnum_p,
                               float* __restrict__ out) {
    __shared__ float uA[NCELL];
    __shared__ float uB[NCELL];
    __shared__ float fs[NCELL];
    __shared__ float as_[NCELL];

    const int b = blockIdx.x;
    const int t = threadIdx.x;
    const int S = *stepnum_p;
    const float c = (float)(DT / DX);  // 0.4096

    const float* row_in = init + (size_t)b * NCELL;

    // Load init into LDS and emit out[0] = init.
    float u0 = row_in[t];
    float u1 = row_in[t + 1024];
    uA[t] = u0;
    uA[t + 1024] = u1;
    out[(size_t)b * NCELL + t] = u0;
    out[(size_t)b * NCELL + t + 1024] = u1;

    float* ucur = uA;
    float* unxt = uB;

    for (int s = 1; s < S; ++s) {
        __syncthreads();  // prev step's unxt writes visible; fs/as reads done
        // Phase 1: per-cell flux and |flux'| into LDS.
        {
            float uc0 = ucur[t];
            float uc1 = ucur[t + 1024];
            fs[t] = flux(uc0);
            as_[t] = flux_prime_abs(uc0);
            fs[t + 1024] = flux(uc1);
            as_[t + 1024] = flux_prime_abs(uc1);
        }
        __syncthreads();
        // Phase 2: stencil update, write LDS next-buffer + global trajectory.
        float* __restrict__ orow = out + (size_t)s * (BATCH * NCELL) + (size_t)b * NCELL;
#pragma unroll
        for (int k = 0; k < 2; ++k) {
            const int j = t + k * 1024;
            // Outflow BC: u_new[0] = u_new[1], u_new[N-1] = u_new[N-2] —
            // boundary threads redundantly compute the neighbor's interior update.
            int jj = j;
            if (j == 0) jj = 1;
            if (j == NCELL - 1) jj = NCELL - 2;
            const float um = ucur[jj - 1], uz = ucur[jj], up = ucur[jj + 1];
            const float fm = fs[jj - 1],  fz = fs[jj],  fp = fs[jj + 1];
            const float am = as_[jj - 1], az = as_[jj], ap = as_[jj + 1];
            const float fh_r = 0.5f * (fz + fp) - 0.5f * fmaxf(az, ap) * (up - uz);
            const float fh_l = 0.5f * (fm + fz) - 0.5f * fmaxf(am, az) * (uz - um);
            const float un = uz - c * (fh_r - fh_l);
            unxt[j] = un;
            orow[j] = un;
        }
        // Swap u buffers.
        float* tmp = ucur;
        ucur = unxt;
        unxt = tmp;
    }
}

extern "C" void kernel_launch(void* const* d_in, const int* in_sizes, int n_in,
                              void* d_out, int out_size, void* d_ws, size_t ws_size,
                              hipStream_t stream) {
    const float* init = (const float*)d_in[0];
    const int* stepnum = (const int*)d_in[1];
    float* out = (float*)d_out;

    dim3 grid(BATCH);
    dim3 block(1024);
    VariantCoeLinear1d_kernel<<<grid, block, 0, stream>>>(init, stepnum, out);
}

// Round 2
// 342.134 us; speedup vs baseline: 1.1241x; 1.1241x over previous
//
#include <hip/hip_runtime.h>

#define BATCH 128
#define NCELL 2048
#define HALO 256            // >= stepnum-2 = 254
#define WIDTH 1536          // 1024 owned + 2*HALO
#define NTHREADS 384        // WIDTH / 4 cells per thread

// flux(u) expanded to a polynomial (beta = 0.1):
// f(u)  = 1.5u + 0.00625u^2 - 0.5166666...u^3 + 0.0125u^4 - 0.00208333...u^6
// f'(u) = 1.5 + 0.0125u - 1.55u^2 + 0.05u^3 - 0.0125u^5
__device__ __forceinline__ float flux_h(float u, float u2) {
    float h = fmaf(u2, -0.0020833333333333333f, 0.0125f);
    h = fmaf(u, h, -0.5166666666666667f);
    h = fmaf(u, h, 0.00625f);
    h = fmaf(u, h, 1.5f);
    return u * h;
}
__device__ __forceinline__ float aprime_h(float u, float u2) {
    float h = fmaf(u2, -0.0125f, 0.05f);
    h = fmaf(u, h, -1.55f);
    h = fmaf(u, h, 0.0125f);
    h = fmaf(u, h, 1.5f);
    return fabsf(h);
}

// Trapezoid time-tiling: 2 blocks per batch row, each owns 1024 cells and
// redundantly computes a halo that shrinks 1 cell/step (max 254). Blocks are
// fully independent -> no inter-block sync. Thread t holds 4 contiguous cells
// in registers; per step: 1 ds_write_b128 (my chunk), 1 barrier, 2 ds_read_b32
// (chunk-edge neighbors), stencil in registers, coalesced float4 store of the
// owned trajectory slice.
__global__ __launch_bounds__(NTHREADS)
void VariantCoeLinear1d_kernel(const float* __restrict__ init,
                               const int* __restrict__ stepnum_p,
                               float* __restrict__ out) {
    __shared__ float ubuf[2][WIDTH];

    const int b = blockIdx.x;
    const int row = b >> 1;
    const int half = b & 1;
    const int t = threadIdx.x;
    const int S = *stepnum_p;
    const float c = 0.4096f;             // float(DT/DX)

    const int ownedLo = half << 10;      // 0 or 1024
    const int ownedHi = ownedLo + 1023;
    const int base = ownedLo - HALO;     // global index of LDS cell 0
    const int li = t << 2;               // my first LDS cell
    const int g0 = base + li;            // my first global cell

    // ---- load init (clamped at row edges; halo beyond the row is garbage
    //      but provably never read) ----
    const float* rin = init + (size_t)row * NCELL;
    float u0, u1, u2, u3;
    if (g0 >= 0 && g0 + 3 < NCELL) {
        float4 v = *(const float4*)(rin + g0);
        u0 = v.x; u1 = v.y; u2 = v.z; u3 = v.w;
    } else {
        u0 = rin[min(max(g0 + 0, 0), NCELL - 1)];
        u1 = rin[min(max(g0 + 1, 0), NCELL - 1)];
        u2 = rin[min(max(g0 + 2, 0), NCELL - 1)];
        u3 = rin[min(max(g0 + 3, 0), NCELL - 1)];
    }

    const bool owned = (t >= HALO / 4) && (t < (HALO + 1024) / 4); // 64..319
    if (owned) {
        *(float4*)(out + (size_t)row * NCELL + g0) = make_float4(u0, u1, u2, u3);
    }

    int cur = 0;
    for (int s = 1; s < S; ++s) {
        float* ub = ubuf[cur];
        *(float4*)&ub[li] = make_float4(u0, u1, u2, u3);
        __syncthreads();

        const int rem = (S - 1) - s;               // remaining steps after s
        const int lo = max(ownedLo - rem, 0);      // active region this step
        const int hi = min(ownedHi + rem, NCELL - 1);

        if (g0 + 3 >= lo && g0 <= hi) {
            const float ulm = ub[max(li - 1, 0)];
            const float ulp = ub[min(li + 4, WIDTH - 1)];
            float ul[6] = {ulm, u0, u1, u2, u3, ulp};
            float f[6], a[6];
#pragma unroll
            for (int j = 0; j < 6; ++j) {
                const float uu = ul[j], uu2 = uu * uu;
                f[j] = flux_h(uu, uu2);
                a[j] = aprime_h(uu, uu2);
            }
            float fh[5];
#pragma unroll
            for (int j = 0; j < 5; ++j) {
                fh[j] = 0.5f * (f[j] + f[j + 1])
                      - 0.5f * fmaxf(a[j], a[j + 1]) * (ul[j + 1] - ul[j]);
            }
            float un[4];
#pragma unroll
            for (int i = 0; i < 4; ++i) {
                un[i] = ul[i + 1] - c * (fh[i + 1] - fh[i]);
                const int g = g0 + i;
                un[i] = (g >= lo && g <= hi) ? un[i] : ul[i + 1];
            }
            // Outflow BC (only edge blocks' edge threads hit these):
            if (g0 == 0) un[0] = un[1];
            if (g0 + 3 == NCELL - 1) un[3] = un[2];
            u0 = un[0]; u1 = un[1]; u2 = un[2]; u3 = un[3];

            if (owned) {
                *(float4*)(out + ((size_t)s * BATCH + row) * NCELL + g0) =
                    make_float4(u0, u1, u2, u3);
            }
        }
        cur ^= 1;
    }
}

extern "C" void kernel_launch(void* const* d_in, const int* in_sizes, int n_in,
                              void* d_out, int out_size, void* d_ws, size_t ws_size,
                              hipStream_t stream) {
    const float* init = (const float*)d_in[0];
    const int* stepnum = (const int*)d_in[1];
    float* out = (float*)d_out;

    dim3 grid(BATCH * 2);   // 2 trapezoid blocks per row -> all 256 CUs
    dim3 block(NTHREADS);
    VariantCoeLinear1d_kernel<<<grid, block, 0, stream>>>(init, stepnum, out);
}

// Round 3
// 327.922 us; speedup vs baseline: 1.1729x; 1.0433x over previous
//
#include <hip/hip_runtime.h>

#define BATCH 128
#define NCELL 2048
#define OWN 512             // cells owned per block
#define HALO 256            // >= stepnum-2 = 254
#define WIDTH 1024          // OWN + 2*HALO
#define NTHREADS 256        // WIDTH / 4 cells per thread

// flux(u) expanded to a polynomial (beta = 0.1):
// f(u)  = 1.5u + 0.00625u^2 - 0.5166666...u^3 + 0.0125u^4 - 0.00208333...u^6
// f'(u) = 1.5 + 0.0125u - 1.55u^2 + 0.05u^3 - 0.0125u^5
__device__ __forceinline__ float flux_h(float u, float u2) {
    float h = fmaf(u2, -0.0020833333333333333f, 0.0125f);
    h = fmaf(u, h, -0.5166666666666667f);
    h = fmaf(u, h, 0.00625f);
    h = fmaf(u, h, 1.5f);
    return u * h;
}
__device__ __forceinline__ float aprime_h(float u, float u2) {
    float h = fmaf(u2, -0.0125f, 0.05f);
    h = fmaf(u, h, -1.55f);
    h = fmaf(u, h, 0.0125f);
    h = fmaf(u, h, 1.5f);
    return fabsf(h);
}

// Trapezoid time-tiling: 4 blocks per batch row (grid=512 -> 2 blocks/CU so
// independent barrier groups overlap). Each block owns 512 cells and
// redundantly computes a halo shrinking 1 cell/step (max 254). No inter-block
// communication. Thread t holds 4 contiguous cells in registers; per step:
// 1 ds_write_b128, 1 barrier, 2 ds_read_b32, stencil in registers, coalesced
// float4 store of the owned trajectory slice.
__global__ __launch_bounds__(NTHREADS)
void VariantCoeLinear1d_kernel(const float* __restrict__ init,
                               const int* __restrict__ stepnum_p,
                               float* __restrict__ out) {
    __shared__ float ubuf[2][WIDTH];

    const int b = blockIdx.x;
    const int row = b >> 2;
    const int q = b & 3;
    const int t = threadIdx.x;
    const int S = *stepnum_p;
    const float c = 0.4096f;             // float(DT/DX)

    const int ownedLo = q * OWN;
    const int ownedHi = ownedLo + OWN - 1;
    const int base = ownedLo - HALO;     // global index of LDS cell 0
    const int li = t << 2;               // my first LDS cell
    const int g0 = base + li;            // my first global cell

    // ---- load init (clamped at row edges; out-of-row halo cells hold the
    //      clamped edge value and are provably never used as real inputs) ----
    const float* rin = init + (size_t)row * NCELL;
    float u0, u1, u2, u3;
    if (g0 >= 0 && g0 + 3 < NCELL) {
        float4 v = *(const float4*)(rin + g0);
        u0 = v.x; u1 = v.y; u2 = v.z; u3 = v.w;
    } else {
        u0 = rin[min(max(g0 + 0, 0), NCELL - 1)];
        u1 = rin[min(max(g0 + 1, 0), NCELL - 1)];
        u2 = rin[min(max(g0 + 2, 0), NCELL - 1)];
        u3 = rin[min(max(g0 + 3, 0), NCELL - 1)];
    }

    const bool owned = (t >= HALO / 4) && (t < (HALO + OWN) / 4); // 64..191
    if (owned) {
        *(float4*)(out + (size_t)row * NCELL + g0) = make_float4(u0, u1, u2, u3);
    }

    int cur = 0;
    for (int s = 1; s < S; ++s) {
        float* ub = ubuf[cur];
        *(float4*)&ub[li] = make_float4(u0, u1, u2, u3);
        __syncthreads();

        const int rem = (S - 1) - s;               // remaining steps after s
        const int lo = max(ownedLo - rem, 0);      // active region this step
        const int hi = min(ownedHi + rem, NCELL - 1);

        if (g0 + 3 >= lo && g0 <= hi) {
            const float ulm = ub[max(li - 1, 0)];
            const float ulp = ub[min(li + 4, WIDTH - 1)];
            float ul[6] = {ulm, u0, u1, u2, u3, ulp};
            float f[6], a[6];
#pragma unroll
            for (int j = 0; j < 6; ++j) {
                const float uu = ul[j], uu2 = uu * uu;
                f[j] = flux_h(uu, uu2);
                a[j] = aprime_h(uu, uu2);
            }
            float fh[5];
#pragma unroll
            for (int j = 0; j < 5; ++j) {
                fh[j] = 0.5f * (f[j] + f[j + 1])
                      - 0.5f * fmaxf(a[j], a[j + 1]) * (ul[j + 1] - ul[j]);
            }
            float un[4];
#pragma unroll
            for (int i = 0; i < 4; ++i) {
                un[i] = ul[i + 1] - c * (fh[i + 1] - fh[i]);
                const int g = g0 + i;
                un[i] = (g >= lo && g <= hi) ? un[i] : ul[i + 1];
            }
            // Outflow BC (only row-edge cells):
            if (g0 == 0) un[0] = un[1];
            if (g0 + 3 == NCELL - 1) un[3] = un[2];
            u0 = un[0]; u1 = un[1]; u2 = un[2]; u3 = un[3];

            if (owned) {
                *(float4*)(out + ((size_t)s * BATCH + row) * NCELL + g0) =
                    make_float4(u0, u1, u2, u3);
            }
        }
        cur ^= 1;
    }
}

extern "C" void kernel_launch(void* const* d_in, const int* in_sizes, int n_in,
                              void* d_out, int out_size, void* d_ws, size_t ws_size,
                              hipStream_t stream) {
    const float* init = (const float*)d_in[0];
    const int* stepnum = (const int*)d_in[1];
    float* out = (float*)d_out;

    dim3 grid(BATCH * 4);   // 4 trapezoid blocks per row -> 2 blocks/CU
    dim3 block(NTHREADS);
    VariantCoeLinear1d_kernel<<<grid, block, 0, stream>>>(init, stepnum, out);
}